// Round 7
// baseline (98.541 us; speedup 1.0000x reference)
//
#include <hip/hip_runtime.h>

#define MSE_W  0.1
#define RANK_W 0.9
#define DIV_W  0.1
#define MARGIN 0.2f

#define BLK   256           // threads per block (4 waves)
#define ROWS  256           // rows per tile (== BLK, 1 row/thread)
#define CCH   64            // columns per tile
#define RATIO (ROWS / CCH)  // 4 column-chunks per diagonal square
#define CHUNK 16            // columns per scalar-load chunk (double-buffered)
#define NCH   (CCH / CHUNK)
#define PAD   1e30f         // pad value -> pair_term contributes exactly 0

// Harness contract: d_ws is re-poisoned to 0xAA BYTES before every launch,
// so a uint counter in ws deterministically starts at 0xAAAAAAAA. The block
// observing old == POISON + nblocks - 1 is the last one -> it finalizes.
#define POISON_U32 0xAAAAAAAAu

// Reference per-pair term, symmetric under (i,j) swap, exactly 0 on the
// diagonal:
//   |dt| > m : max(m - sign(dt)*dp, 0)   (covers both hi and lo branches)
//   |dt| <= m: 0.1*|dp|
// 10 VALU ops: sub,sub,and,xor,sub,max,mul,cmp(|x| mod),cndmask,add.
__device__ __forceinline__ float pair_term(float pi, float ti, float f, float g) {
    const float dp = pi - f;
    const float dt = ti - g;
    const unsigned sgn = __float_as_uint(dt) & 0x80000000u;
    const float y = __uint_as_float(__float_as_uint(dp) ^ sgn);
    const float outer = fmaxf(MARGIN - y, 0.0f);
    const float mid   = 0.1f * fabsf(dp);
    return (fabsf(dt) > MARGIN) ? outer : mid;
}

// ws layout (floats): [0..nparts-1] weighted tile partials,
// [nparts..nparts+4] moments (se,p,p2,t,t2), [nparts+5] uint done-counter.
__global__ __launch_bounds__(BLK)
void fused_loss(const float* __restrict__ pred, const float* __restrict__ tgt,
                int n, int gcols, int grows, float* __restrict__ ws,
                int nparts, unsigned int nblocks, float* __restrict__ out) {
    __shared__ float sred[BLK / 64];
    __shared__ int   is_last;
    const int tid = threadIdx.x;
    const int bid = blockIdx.x;
    float* partials = ws;
    float* moments  = ws + nparts;
    unsigned int* cnt = (unsigned int*)(ws + nparts + 5);

    // Decode bid -> (rb, cb) over the triangle tile set (scalar, <= grows iters).
    int rb = 0, off = 0;
    for (; rb + 1 < grows; ++rb) {
        int c = gcols - RATIO * rb;
        if (c < 0) c = 0;
        if (bid < off + c) break;
        off += c;
    }
    const int cb = RATIO * rb + (bid - off);
    const float w = (cb < RATIO * (rb + 1)) ? 0.5f : 1.0f;

    // One row per thread; PAD rows/cols contribute exactly 0 (no masking).
    const int i = rb * ROWS + tid;
    const float pi = (i < n) ? pred[i] : PAD;
    const float ti = (i < n) ? tgt[i]  : PAD;
    float acc0 = 0.0f, acc1 = 0.0f;   // 2 chains for add-latency ILP

    const int jbase = cb * CCH;
    if (jbase + CCH <= n) {
        // Column addresses are wave-uniform -> scalar-cache loads (SGPRs),
        // no VALU->SGPR hazards; 2-deep chunk pipeline hides them.
        const float* __restrict__ cp = pred + jbase;
        const float* __restrict__ ct = tgt  + jbase;
        float f[2][CHUNK], g[2][CHUNK];
        #pragma unroll
        for (int q = 0; q < CHUNK; ++q) { f[0][q] = cp[q]; g[0][q] = ct[q]; }
        #pragma unroll
        for (int c = 0; c < NCH; ++c) {
            const int cur = c & 1;
            if (c + 1 < NCH) {
                const int nxt = cur ^ 1;
                const int base = (c + 1) * CHUNK;
                #pragma unroll
                for (int q = 0; q < CHUNK; ++q) {
                    f[nxt][q] = cp[base + q];
                    g[nxt][q] = ct[base + q];
                }
            }
            #pragma unroll
            for (int q = 0; q < CHUNK; q += 2) {
                acc0 += pair_term(pi, ti, f[cur][q],     g[cur][q]);
                acc1 += pair_term(pi, ti, f[cur][q + 1], g[cur][q + 1]);
            }
        }
    } else {
        for (int s = 0; s < CCH; ++s) {
            const int j = jbase + s;
            const float fv = (j < n) ? pred[j] : PAD;
            const float gv = (j < n) ? tgt[j]  : PAD;
            acc0 += pair_term(pi, ti, fv, gv);
        }
    }

    // Block reduce -> one weighted plain store per tile.
    float a = acc0 + acc1;
    #pragma unroll
    for (int offs = 32; offs > 0; offs >>= 1) a += __shfl_down(a, offs, 64);
    if ((tid & 63) == 0) sred[tid >> 6] = a;
    __syncthreads();
    if (tid == 0) {
        float s = 0.0f;
        #pragma unroll
        for (int wv = 0; wv < BLK / 64; ++wv) s += sred[wv];
        partials[bid] = s * w;
    }

    // Block 0 also computes the moments (overlaps with other tiles' rounds).
    if (bid == 0) {
        __shared__ float smom[5][BLK / 64];
        float se = 0.f, p = 0.f, p2 = 0.f, t = 0.f, t2 = 0.f;
        for (int k = tid; k < n; k += BLK) {
            const float pv = pred[k];
            const float tv = tgt[k];
            const float d  = pv - tv;
            se += d * d;
            p += pv; p2 += pv * pv;
            t += tv; t2 += tv * tv;
        }
        #pragma unroll
        for (int offs = 32; offs > 0; offs >>= 1) {
            se += __shfl_down(se, offs, 64);
            p  += __shfl_down(p,  offs, 64);
            p2 += __shfl_down(p2, offs, 64);
            t  += __shfl_down(t,  offs, 64);
            t2 += __shfl_down(t2, offs, 64);
        }
        if ((tid & 63) == 0) {
            const int wv = tid >> 6;
            smom[0][wv] = se; smom[1][wv] = p; smom[2][wv] = p2;
            smom[3][wv] = t;  smom[4][wv] = t2;
        }
        __syncthreads();
        if (tid == 0) {
            #pragma unroll
            for (int k = 0; k < 5; ++k) {
                float s = 0.0f;
                #pragma unroll
                for (int wv = 0; wv < BLK / 64; ++wv) s += smom[k][wv];
                moments[k] = s;
            }
        }
    }

    // Last-block-done handoff (release fence -> device-scope atomic -> acquire).
    if (tid == 0) {
        __threadfence();                              // release our stores
        const unsigned int old = atomicAdd(cnt, 1u);  // device scope by default
        is_last = (old == POISON_U32 + nblocks - 1u);
    }
    __syncthreads();
    if (!is_last) return;
    __threadfence();                                  // acquire others' stores

    // Final reduction of 2112 partials + combine (runs once, ~1 us).
    float rk = 0.0f;
    for (int k = tid; k < nparts; k += BLK) rk += partials[k];
    #pragma unroll
    for (int offs = 32; offs > 0; offs >>= 1) rk += __shfl_down(rk, offs, 64);
    if ((tid & 63) == 0) sred[tid >> 6] = rk;
    __syncthreads();
    if (tid == 0) {
        double R = 0;
        #pragma unroll
        for (int wv = 0; wv < BLK / 64; ++wv) R += sred[wv];
        const double SE = moments[0];
        const double P  = moments[1];
        const double P2 = moments[2];
        const double T  = moments[3];
        const double T2 = moments[4];
        const double nn = (double)n;
        const double pair_count = nn * (nn - 1.0) * 0.5;
        const double rank  = R / pair_count;   // weighted partials == S_upper
        const double mse   = SE / nn;
        const double var_p = (P2 - P * P / nn) / (nn - 1.0);
        const double var_t = (T2 - T * T / nn) / (nn - 1.0);
        double div = var_t - var_p;
        if (div < 0.0) div = 0.0;
        out[0] = (float)(MSE_W * mse + RANK_W * rank + DIV_W * div);
    }
}

extern "C" void kernel_launch(void* const* d_in, const int* in_sizes, int n_in,
                              void* d_out, int out_size, void* d_ws, size_t ws_size,
                              hipStream_t stream) {
    const float* pred = (const float*)d_in[0];
    const float* tgt  = (const float*)d_in[1];
    const int n = in_sizes[0];
    float* ws  = (float*)d_ws;
    float* out = (float*)d_out;

    const int gcols = (n + CCH - 1) / CCH;    // 128 for n=8192
    const int grows = (n + ROWS - 1) / ROWS;  // 32
    int nblocks = 0;                          // triangle tile count (2112 @8192)
    for (int rb = 0; rb < grows; ++rb) {
        const int cnt = gcols - RATIO * rb;
        nblocks += (cnt > 0) ? cnt : 0;
    }

    fused_loss<<<nblocks, BLK, 0, stream>>>(pred, tgt, n, gcols, grows, ws,
                                            nblocks, (unsigned int)nblocks, out);
}

// Round 8
// 66.078 us; speedup vs baseline: 1.4913x; 1.4913x over previous
//
#include <hip/hip_runtime.h>

// ROUND 8: revert of the round-7 last-block fusion. Post-mortem evidence:
// per-block __threadfence() (device-scope release -> buffer_wbl2 sc1 +
// vmcnt(0) drain) executed by all 2112 blocks cost ~42 us of stall
// (VALUBusy 13.5% over 48.6 us). The two-dispatch structure's implicit
// barrier is far cheaper than 2112 device fences. Known-good: 66.3 us.

#define MSE_W  0.1
#define RANK_W 0.9
#define DIV_W  0.1
#define MARGIN 0.2f

#define BLK   256           // threads per block (4 waves)
#define ROWS  256           // rows per tile (== BLK, 1 row/thread)
#define CCH   64            // columns per tile
#define RATIO (ROWS / CCH)  // 4 column-chunks per diagonal square
#define CHUNK 16            // columns per scalar-load chunk (double-buffered)
#define NCH   (CCH / CHUNK)
#define PAD   1e30f         // pad value -> pair_term contributes exactly 0

// Reference per-pair term, symmetric under (i,j) swap, exactly 0 on the
// diagonal:
//   |dt| > m : max(m - sign(dt)*dp, 0)   (covers both hi and lo branches)
//   |dt| <= m: 0.1*|dp|
// 10 VALU ops: sub,sub,and,xor,sub,max,mul,cmp(|x| mod),cndmask,add.
__device__ __forceinline__ float pair_term(float pi, float ti, float f, float g) {
    const float dp = pi - f;
    const float dt = ti - g;
    const unsigned sgn = __float_as_uint(dt) & 0x80000000u;
    const float y = __uint_as_float(__float_as_uint(dp) ^ sgn);
    const float outer = fmaxf(MARGIN - y, 0.0f);
    const float mid   = 0.1f * fabsf(dp);
    return (fabsf(dt) > MARGIN) ? outer : mid;
}

// Triangle-tiled, 256x64 tiles (8448 waves ~= 8.25 rounds on 1024 SIMDs).
//   cb >= RATIO*(rb+1): strictly above the diagonal squares, weight 1
//   cb in [RATIO*rb, RATIO*(rb+1)): inside a 256-wide diagonal square, weight 1/2
// S_upper = sum(above) + sum(diag)/2; weighted partials sum directly to S_upper.
// Block 0 additionally computes the moments (overlapped with other tiles' rounds).
__global__ __launch_bounds__(BLK)
void pair_partials(const float* __restrict__ pred, const float* __restrict__ tgt,
                   int n, int gcols, int grows, float* __restrict__ partials,
                   int nparts) {
    __shared__ float sred[BLK / 64];
    const int tid = threadIdx.x;
    const int bid = blockIdx.x;

    // Decode bid -> (rb, cb) over the triangle tile set (scalar, <= grows iters).
    int rb = 0, off = 0;
    for (; rb + 1 < grows; ++rb) {
        int cnt = gcols - RATIO * rb;
        if (cnt < 0) cnt = 0;
        if (bid < off + cnt) break;
        off += cnt;
    }
    const int cb = RATIO * rb + (bid - off);
    const float w = (cb < RATIO * (rb + 1)) ? 0.5f : 1.0f;

    // One row per thread; PAD rows/cols contribute exactly 0 (no masking).
    const int i = rb * ROWS + tid;
    const float pi = (i < n) ? pred[i] : PAD;
    const float ti = (i < n) ? tgt[i]  : PAD;
    float acc0 = 0.0f, acc1 = 0.0f;   // 2 chains for add-latency ILP

    const int jbase = cb * CCH;
    if (jbase + CCH <= n) {
        // Column addresses are wave-uniform -> scalar-cache loads (SGPRs),
        // no VALU->SGPR hazards; 2-deep chunk pipeline hides them.
        const float* __restrict__ cp = pred + jbase;
        const float* __restrict__ ct = tgt  + jbase;
        float f[2][CHUNK], g[2][CHUNK];
        #pragma unroll
        for (int q = 0; q < CHUNK; ++q) { f[0][q] = cp[q]; g[0][q] = ct[q]; }
        #pragma unroll
        for (int c = 0; c < NCH; ++c) {
            const int cur = c & 1;
            if (c + 1 < NCH) {
                const int nxt = cur ^ 1;
                const int base = (c + 1) * CHUNK;
                #pragma unroll
                for (int q = 0; q < CHUNK; ++q) {
                    f[nxt][q] = cp[base + q];
                    g[nxt][q] = ct[base + q];
                }
            }
            #pragma unroll
            for (int q = 0; q < CHUNK; q += 2) {
                acc0 += pair_term(pi, ti, f[cur][q],     g[cur][q]);
                acc1 += pair_term(pi, ti, f[cur][q + 1], g[cur][q + 1]);
            }
        }
    } else {
        for (int s = 0; s < CCH; ++s) {
            const int j = jbase + s;
            const float fv = (j < n) ? pred[j] : PAD;
            const float gv = (j < n) ? tgt[j]  : PAD;
            acc0 += pair_term(pi, ti, fv, gv);
        }
    }

    // Block reduce -> one weighted store per tile (no atomics, no ws init).
    float a = acc0 + acc1;
    #pragma unroll
    for (int offs = 32; offs > 0; offs >>= 1) a += __shfl_down(a, offs, 64);
    if ((tid & 63) == 0) sred[tid >> 6] = a;
    __syncthreads();
    if (tid == 0) {
        float s = 0.0f;
        #pragma unroll
        for (int wv = 0; wv < BLK / 64; ++wv) s += sred[wv];
        partials[bid] = s * w;
    }

    // Block 0 also computes the moments; overlaps with other tiles' rounds.
    if (bid == 0) {
        __shared__ float smom[5][BLK / 64];
        float se = 0.f, p = 0.f, p2 = 0.f, t = 0.f, t2 = 0.f;
        for (int k = tid; k < n; k += BLK) {
            const float pv = pred[k];
            const float tv = tgt[k];
            const float d  = pv - tv;
            se += d * d;
            p += pv; p2 += pv * pv;
            t += tv; t2 += tv * tv;
        }
        #pragma unroll
        for (int offs = 32; offs > 0; offs >>= 1) {
            se += __shfl_down(se, offs, 64);
            p  += __shfl_down(p,  offs, 64);
            p2 += __shfl_down(p2, offs, 64);
            t  += __shfl_down(t,  offs, 64);
            t2 += __shfl_down(t2, offs, 64);
        }
        if ((tid & 63) == 0) {
            const int wv = tid >> 6;
            smom[0][wv] = se; smom[1][wv] = p; smom[2][wv] = p2;
            smom[3][wv] = t;  smom[4][wv] = t2;
        }
        __syncthreads();
        if (tid == 0) {
            #pragma unroll
            for (int k = 0; k < 5; ++k) {
                float s = 0.0f;
                #pragma unroll
                for (int wv = 0; wv < BLK / 64; ++wv) s += smom[k][wv];
                partials[nparts + k] = s;
            }
        }
    }
}

__global__ __launch_bounds__(256)
void finalize_kernel(const float* __restrict__ partials, int nparts, int n,
                     float* __restrict__ out) {
    __shared__ float sm[4];
    const int tid = threadIdx.x;

    float rk = 0.0f;
    for (int i = tid; i < nparts; i += 256) rk += partials[i];
    #pragma unroll
    for (int off = 32; off > 0; off >>= 1) rk += __shfl_down(rk, off, 64);
    if ((tid & 63) == 0) sm[tid >> 6] = rk;
    __syncthreads();
    if (tid == 0) {
        double R = 0;
        #pragma unroll
        for (int wv = 0; wv < 4; ++wv) R += sm[wv];
        const double SE = partials[nparts + 0];
        const double P  = partials[nparts + 1];
        const double P2 = partials[nparts + 2];
        const double T  = partials[nparts + 3];
        const double T2 = partials[nparts + 4];
        const double nn = (double)n;
        const double pair_count = nn * (nn - 1.0) * 0.5;
        const double rank  = R / pair_count;   // weighted partials == S_upper
        const double mse   = SE / nn;
        const double var_p = (P2 - P * P / nn) / (nn - 1.0);
        const double var_t = (T2 - T * T / nn) / (nn - 1.0);
        double div = var_t - var_p;
        if (div < 0.0) div = 0.0;
        out[0] = (float)(MSE_W * mse + RANK_W * rank + DIV_W * div);
    }
}

extern "C" void kernel_launch(void* const* d_in, const int* in_sizes, int n_in,
                              void* d_out, int out_size, void* d_ws, size_t ws_size,
                              hipStream_t stream) {
    const float* pred = (const float*)d_in[0];
    const float* tgt  = (const float*)d_in[1];
    const int n = in_sizes[0];
    float* ws  = (float*)d_ws;
    float* out = (float*)d_out;

    const int gcols = (n + CCH - 1) / CCH;    // 128 for n=8192
    const int grows = (n + ROWS - 1) / ROWS;  // 32
    int nblocks = 0;                          // triangle tile count (2112 @8192)
    for (int rb = 0; rb < grows; ++rb) {
        const int cnt = gcols - RATIO * rb;
        nblocks += (cnt > 0) ? cnt : 0;
    }

    pair_partials<<<nblocks, BLK, 0, stream>>>(pred, tgt, n, gcols, grows, ws, nblocks);
    finalize_kernel<<<1, 256, 0, stream>>>(ws, nblocks, n, out);
}